// Round 2
// baseline (23176.579 us; speedup 1.0000x reference)
//
#include <hip/hip_runtime.h>
#include <math.h>

#define HID 2048
#define VOC 28
#define TLEN 512
#define NBLK 256
#define NTHR 512
#define FSTRIDE 16   // flags padded to one 64B line each

// ---------------------------------------------------------------------------
// K1: xp[v][row] = sum_k emb[v][k] * Wih[row][k] + bih[row] + bhh[row]
// ---------------------------------------------------------------------------
__global__ __launch_bounds__(256) void k_xproj(
    const float* __restrict__ emb, const float* __restrict__ Wih,
    const float* __restrict__ bih, const float* __restrict__ bhh,
    float* __restrict__ xp)
{
  const int slab = blockIdx.x;      // rows [slab*32, slab*32+32)
  const int t = threadIdx.x;
  const int v = t & 31;             // vocab lane (>=28 inactive)
  const int sub = t >> 5;           // 8 column groups of 32 (per 256-chunk)
  const int w = t >> 6;             // wave id (4)
  __shared__ float embl[VOC][257];  // +1 pad: conflict-free row access
  __shared__ float red[4][32][33];  // +1 pad
  float acc[32];
#pragma unroll
  for (int r = 0; r < 32; ++r) acc[r] = 0.f;
  const int vv = (v < VOC) ? v : 0;
  for (int c = 0; c < 8; ++c) {
    __syncthreads();
    for (int e = t; e < VOC * 256; e += 256) {
      int ev = e >> 8, ek = e & 255;
      embl[ev][ek] = emb[ev * HID + c * 256 + ek];
    }
    __syncthreads();
    float el[32];
#pragma unroll
    for (int i = 0; i < 32; ++i) el[i] = embl[vv][sub * 32 + i];
    for (int r = 0; r < 32; ++r) {
      const float4* wr = (const float4*)(Wih + (size_t)(slab * 32 + r) * HID + c * 256 + sub * 32);
      float a = acc[r];
#pragma unroll
      for (int q = 0; q < 8; ++q) {
        float4 wv = wr[q];
        a = fmaf(el[q * 4 + 0], wv.x, a);
        a = fmaf(el[q * 4 + 1], wv.y, a);
        a = fmaf(el[q * 4 + 2], wv.z, a);
        a = fmaf(el[q * 4 + 3], wv.w, a);
      }
      acc[r] = a;
    }
  }
#pragma unroll
  for (int r = 0; r < 32; ++r) acc[r] += __shfl_xor(acc[r], 32);
  if ((t & 32) == 0) {
#pragma unroll
    for (int r = 0; r < 32; ++r) red[w][v][r] = acc[r];
  }
  __syncthreads();
  for (int p = t; p < VOC * 32; p += 256) {
    int pv = p >> 5, pr = p & 31;
    float s = red[0][pv][pr] + red[1][pv][pr] + red[2][pv][pr] + red[3][pv][pr];
    int row = slab * 32 + pr;
    xp[(size_t)pv * (4 * HID) + row] = s + bih[row] + bhh[row];
  }
}

// ---------------------------------------------------------------------------
// Persistent cooperative LSTM kernel with flag-vector barrier (no atomic RMW).
// 256 blocks x 512 thr. Block b owns hidden j in [8b, 8b+8) -> 32 gate rows.
// ---------------------------------------------------------------------------
struct MainArgs {
  const float* enc_Whh;
  const float* dec_Whh;
  const int* x;
  const int* target;
  const float* eps;
  const float* mu_W; const float* mu_b;
  const float* lv_W; const float* lv_b;
  const float* xp_enc; const float* xp_dec;
  float* h_buf0; float* h_buf1;   // double-buffered h (2048 each)
  unsigned* flags;                // 256 slots, 64B apart, monotone epochs
  float* out_res; float* out_dec; float* out_mu; float* out_lv;
};

// Caller must __syncthreads() after the data stores, BEFORE arrive.
__device__ __forceinline__ void flag_arrive(unsigned* flags, int b, unsigned e) {
  if (threadIdx.x == 0) {
    __threadfence();   // publish this block's stores (agent scope)
    __hip_atomic_store(&flags[b * FSTRIDE], e, __ATOMIC_RELAXED,
                       __HIP_MEMORY_SCOPE_AGENT);
  }
}
__device__ __forceinline__ void flag_wait(const unsigned* flags, unsigned e) {
  const int t = threadIdx.x;
  if (t < NBLK) {
    // acquire poll: one flag per thread, 256 distinct cachelines
    while (__hip_atomic_load(&flags[t * FSTRIDE], __ATOMIC_ACQUIRE,
                             __HIP_MEMORY_SCOPE_AGENT) < e) {}
  }
  __syncthreads();
}

__global__ __launch_bounds__(NTHR) void k_main(MainArgs a) {
  const int b = blockIdx.x;
  const int t = threadIdx.x;
  const int base_j = b * 8;
  const int r = t >> 4;           // 0..31 : gate*8 + jj
  const int cs = t & 15;
  const int gate = r >> 3;
  const int jj = r & 7;
  const size_t row_g = (size_t)gate * HID + base_j + jj;

  __shared__ float h_lds[HID];
  __shared__ float gsum[32];
  __shared__ float xparr[32];
  __shared__ int toks[2 * TLEN];

  toks[t] = a.x[t];
  toks[TLEN + t] = (t == 0) ? 0 : a.target[t - 1];
  if (t < 8) a.h_buf0[base_j + t] = 0.f;   // h0 = 0
  float c_reg = 0.f;                        // c0 = 0 (held by t<8)

  float4 w4[32];
  {
    const float* wp = a.enc_Whh + row_g * HID + cs * 4;
#pragma unroll
    for (int m = 0; m < 32; ++m) w4[m] = *(const float4*)(wp + m * 64);
  }
  float* hb[2] = {a.h_buf0, a.h_buf1};
  int ping = 0;
  unsigned epoch = 1;
  __syncthreads();
  flag_arrive(a.flags, b, epoch);
  flag_wait(a.flags, epoch);

  for (int phase = 0; phase < 2; ++phase) {
    const float* xp = phase ? a.xp_dec : a.xp_enc;
    const int* tk = &toks[phase * TLEN];
    for (int s = 0; s < TLEN; ++s) {
      const float* hb_r = hb[ping];
      float* hb_w = hb[ping ^ 1];
      float4 hv = ((const float4*)hb_r)[t];
      float xpv = 0.f;
      if (t < 32) xpv = xp[(size_t)tk[s] * (4 * HID) + (t >> 3) * HID + base_j + (t & 7)];
      ((float4*)h_lds)[t] = hv;
      if (t < 32) xparr[t] = xpv;
      __syncthreads();
      float acc = 0.f;
      const float4* h4 = (const float4*)h_lds;
#pragma unroll
      for (int m = 0; m < 32; ++m) {
        float4 hh = h4[(m << 4) + cs];
        float4 ww = w4[m];
        acc = fmaf(ww.x, hh.x, acc);
        acc = fmaf(ww.y, hh.y, acc);
        acc = fmaf(ww.z, hh.z, acc);
        acc = fmaf(ww.w, hh.w, acc);
      }
      acc += __shfl_xor(acc, 1);
      acc += __shfl_xor(acc, 2);
      acc += __shfl_xor(acc, 4);
      acc += __shfl_xor(acc, 8);
      if (cs == 0) gsum[r] = acc;
      __syncthreads();
      // parallel activations: lanes 0-31 of wave 0 (i,f,g,o blocks of 8)
      if (t < 32) {
        float g = gsum[t] + xparr[t];
        bool is_g = (t >= 16) && (t < 24);
        float act = is_g ? tanhf(g) : (1.f / (1.f + expf(-g)));
        float sf = __shfl(act, (t & 7) + 8);
        float tg = __shfl(act, (t & 7) + 16);
        float so = __shfl(act, (t & 7) + 24);
        if (t < 8) {
          float si = act;
          c_reg = sf * c_reg + si * tg;
          float hn = so * tanhf(c_reg);
          hb_w[base_j + t] = hn;
          if (phase) a.out_dec[(size_t)s * HID + base_j + t] = hn;
        }
      }
      __syncthreads();
      ++epoch;
      flag_arrive(a.flags, b, epoch);
      flag_wait(a.flags, epoch);
      ping ^= 1;
    }
    if (phase == 0) {
      // ---- mu / logvar / z (h_enc is in hb[ping]) ----
      float4 hv = ((const float4*)hb[ping])[t];
      ((float4*)h_lds)[t] = hv;
      __syncthreads();
      const int r16 = t >> 5, cs32 = t & 31;    // 16 rows x 32 lanes
      const int mrow = base_j + (r16 & 7);
      const float* Wrow = (r16 < 8 ? a.mu_W : a.lv_W) + (size_t)mrow * HID + cs32 * 4;
      float acc = 0.f;
      const float4* h4 = (const float4*)h_lds;
#pragma unroll
      for (int m = 0; m < 16; ++m) {
        float4 wv = *(const float4*)(Wrow + m * 128);
        float4 hh = h4[(m << 5) + cs32];
        acc = fmaf(wv.x, hh.x, acc);
        acc = fmaf(wv.y, hh.y, acc);
        acc = fmaf(wv.z, hh.z, acc);
        acc = fmaf(wv.w, hh.w, acc);
      }
      acc += __shfl_xor(acc, 1);
      acc += __shfl_xor(acc, 2);
      acc += __shfl_xor(acc, 4);
      acc += __shfl_xor(acc, 8);
      acc += __shfl_xor(acc, 16);
      if (cs32 == 0) gsum[r16] = acc + (r16 < 8 ? a.mu_b[mrow] : a.lv_b[mrow]);
      __syncthreads();
      if (t < 8) {
        float mu = gsum[t], lv = gsum[8 + t];
        a.out_mu[base_j + t] = mu;
        a.out_lv[base_j + t] = lv;
        // z -> the buffer nobody reads this phase (hb[ping^1])
        hb[ping ^ 1][base_j + t] = fmaf(a.eps[base_j + t], expf(0.5f * lv), mu);
      }
      // reload weights for decoder
      {
        const float* wp = a.dec_Whh + row_g * HID + cs * 4;
#pragma unroll
        for (int m = 0; m < 32; ++m) w4[m] = *(const float4*)(wp + m * 64);
      }
      __syncthreads();
      ++epoch;
      flag_arrive(a.flags, b, epoch);
      flag_wait(a.flags, epoch);
      ping ^= 1;   // decoder reads z from hb[ping]
    }
  }
}

// ---------------------------------------------------------------------------
// Argmax over each dec_outs row (first-index tie semantics, like jnp.argmax)
// ---------------------------------------------------------------------------
__global__ __launch_bounds__(256) void k_argmax(const float* __restrict__ dec,
                                               float* __restrict__ res) {
  const int row = blockIdx.x;
  const int t = threadIdx.x;
  const float4* d4 = (const float4*)(dec + (size_t)row * HID);
  float bv = -INFINITY; int bi = 0;
#pragma unroll
  for (int k = 0; k < 2; ++k) {
    int p = t + k * 256;
    float4 v = d4[p];
    int i0 = p * 4;
    if (v.x > bv) { bv = v.x; bi = i0; }
    if (v.y > bv) { bv = v.y; bi = i0 + 1; }
    if (v.z > bv) { bv = v.z; bi = i0 + 2; }
    if (v.w > bv) { bv = v.w; bi = i0 + 3; }
  }
  for (int off = 1; off < 64; off <<= 1) {
    float ov = __shfl_xor(bv, off);
    int oi = __shfl_xor(bi, off);
    if (ov > bv || (ov == bv && oi < bi)) { bv = ov; bi = oi; }
  }
  __shared__ float sv[4];
  __shared__ int si[4];
  if ((t & 63) == 0) { sv[t >> 6] = bv; si[t >> 6] = bi; }
  __syncthreads();
  if (t == 0) {
    for (int ww = 1; ww < 4; ++ww)
      if (sv[ww] > bv || (sv[ww] == bv && si[ww] < bi)) { bv = sv[ww]; bi = si[ww]; }
    res[row] = (float)bi;
  }
}

// ---------------------------------------------------------------------------
extern "C" void kernel_launch(void* const* d_in, const int* in_sizes, int n_in,
                              void* d_out, int out_size, void* d_ws, size_t ws_size,
                              hipStream_t stream) {
  (void)in_sizes; (void)n_in; (void)out_size; (void)ws_size;
  const int* x        = (const int*)d_in[0];
  const int* target   = (const int*)d_in[1];
  const float* eps    = (const float*)d_in[2];
  const float* enc_emb = (const float*)d_in[3];
  const float* enc_Wih = (const float*)d_in[4];
  const float* enc_Whh = (const float*)d_in[5];
  const float* enc_bih = (const float*)d_in[6];
  const float* enc_bhh = (const float*)d_in[7];
  const float* mu_W   = (const float*)d_in[8];
  const float* mu_b   = (const float*)d_in[9];
  const float* lv_W   = (const float*)d_in[10];
  const float* lv_b   = (const float*)d_in[11];
  const float* dec_emb = (const float*)d_in[12];
  const float* dec_Wih = (const float*)d_in[13];
  const float* dec_Whh = (const float*)d_in[14];
  const float* dec_bih = (const float*)d_in[15];
  const float* dec_bhh = (const float*)d_in[16];

  float* out = (float*)d_out;
  char* ws = (char*)d_ws;
  unsigned* flags = (unsigned*)ws;                     // 256 * 64B = 16 KB
  float* h_buf0 = (float*)(ws + NBLK * FSTRIDE * 4);   // 8 KB
  float* h_buf1 = h_buf0 + HID;                        // 8 KB
  float* xp_enc = h_buf1 + HID;                        // 28*8192 f32
  float* xp_dec = xp_enc + VOC * 4 * HID;

  hipMemsetAsync(flags, 0, NBLK * FSTRIDE * 4, stream);
  k_xproj<<<NBLK, 256, 0, stream>>>(enc_emb, enc_Wih, enc_bih, enc_bhh, xp_enc);
  k_xproj<<<NBLK, 256, 0, stream>>>(dec_emb, dec_Wih, dec_bih, dec_bhh, xp_dec);

  MainArgs a;
  a.enc_Whh = enc_Whh; a.dec_Whh = dec_Whh;
  a.x = x; a.target = target; a.eps = eps;
  a.mu_W = mu_W; a.mu_b = mu_b; a.lv_W = lv_W; a.lv_b = lv_b;
  a.xp_enc = xp_enc; a.xp_dec = xp_dec;
  a.h_buf0 = h_buf0; a.h_buf1 = h_buf1;
  a.flags = flags;
  a.out_res = out;
  a.out_dec = out + TLEN;
  a.out_mu  = out + TLEN + (size_t)TLEN * HID;
  a.out_lv  = out + TLEN + (size_t)TLEN * HID + HID;

  void* kargs[] = {(void*)&a};
  hipLaunchCooperativeKernel((void*)k_main, dim3(NBLK), dim3(NTHR), kargs, 0, stream);

  k_argmax<<<TLEN, 256, 0, stream>>>(out + TLEN, out);
}

// Round 3
// 6571.756 us; speedup vs baseline: 3.5267x; 3.5267x over previous
//
#include <hip/hip_runtime.h>
#include <math.h>

#define HID 2048
#define VOC 28
#define TLEN 512
#define NBLK 256
#define NTHR 512

#define ATOM_ST(p, v) __hip_atomic_store((p), (v), __ATOMIC_RELAXED, __HIP_MEMORY_SCOPE_AGENT)
#define ATOM_LD(p)    __hip_atomic_load((p), __ATOMIC_RELAXED, __HIP_MEMORY_SCOPE_AGENT)

// ---------------------------------------------------------------------------
// K1: xp[v][row] = sum_k emb[v][k] * Wih[row][k] + bih[row] + bhh[row]
// ---------------------------------------------------------------------------
__global__ __launch_bounds__(256) void k_xproj(
    const float* __restrict__ emb, const float* __restrict__ Wih,
    const float* __restrict__ bih, const float* __restrict__ bhh,
    float* __restrict__ xp)
{
  const int slab = blockIdx.x;      // rows [slab*32, slab*32+32)
  const int t = threadIdx.x;
  const int v = t & 31;             // vocab lane (>=28 inactive)
  const int sub = t >> 5;           // 8 column groups of 32 (per 256-chunk)
  const int w = t >> 6;             // wave id (4)
  __shared__ float embl[VOC][257];  // +1 pad: conflict-free row access
  __shared__ float red[4][32][33];  // +1 pad
  float acc[32];
#pragma unroll
  for (int r = 0; r < 32; ++r) acc[r] = 0.f;
  const int vv = (v < VOC) ? v : 0;
  for (int c = 0; c < 8; ++c) {
    __syncthreads();
    for (int e = t; e < VOC * 256; e += 256) {
      int ev = e >> 8, ek = e & 255;
      embl[ev][ek] = emb[ev * HID + c * 256 + ek];
    }
    __syncthreads();
    float el[32];
#pragma unroll
    for (int i = 0; i < 32; ++i) el[i] = embl[vv][sub * 32 + i];
    for (int r = 0; r < 32; ++r) {
      const float4* wr = (const float4*)(Wih + (size_t)(slab * 32 + r) * HID + c * 256 + sub * 32);
      float a = acc[r];
#pragma unroll
      for (int q = 0; q < 8; ++q) {
        float4 wv = wr[q];
        a = fmaf(el[q * 4 + 0], wv.x, a);
        a = fmaf(el[q * 4 + 1], wv.y, a);
        a = fmaf(el[q * 4 + 2], wv.z, a);
        a = fmaf(el[q * 4 + 3], wv.w, a);
      }
      acc[r] = a;
    }
  }
#pragma unroll
  for (int r = 0; r < 32; ++r) acc[r] += __shfl_xor(acc[r], 32);
  if ((t & 32) == 0) {
#pragma unroll
    for (int r = 0; r < 32; ++r) red[w][v][r] = acc[r];
  }
  __syncthreads();
  for (int p = t; p < VOC * 32; p += 256) {
    int pv = p >> 5, pr = p & 31;
    float s = red[0][pv][pr] + red[1][pv][pr] + red[2][pv][pr] + red[3][pv][pr];
    int row = slab * 32 + pr;
    xp[(size_t)pv * (4 * HID) + row] = s + bih[row] + bhh[row];
  }
}

// ---------------------------------------------------------------------------
// Persistent cooperative LSTM kernel. All cross-block state (h, flags) moves
// through RELAXED agent-scope atomics (LLC-coherent, L2-bypassing) — zero
// buffer_wbl2 / buffer_inv in the steady state. Ordering: __syncthreads
// drains vmcnt(0) before s_barrier, so data stores are globally visible
// before the flag store issues.
// ---------------------------------------------------------------------------
struct MainArgs {
  const float* enc_Whh;
  const float* dec_Whh;
  const int* x;
  const int* target;
  const float* eps;
  const float* mu_W; const float* mu_b;
  const float* lv_W; const float* lv_b;
  const float* xp_enc; const float* xp_dec;
  float* h_buf0; float* h_buf1;   // double-buffered h (2048 each)
  unsigned* flags;                // 256 contiguous epoch slots
  float* out_res; float* out_dec; float* out_mu; float* out_lv;
};

// Precondition: __syncthreads() executed since the data stores (vmcnt drained).
__device__ __forceinline__ void flag_arrive(unsigned* flags, int b, unsigned e) {
  if (threadIdx.x == 0) ATOM_ST(&flags[b], e);
}
__device__ __forceinline__ void flag_wait(unsigned* flags, unsigned e) {
  const int t = threadIdx.x;
  if (t < NBLK) {
    while (ATOM_LD(&flags[t]) < e) { }
  }
  __atomic_signal_fence(__ATOMIC_ACQUIRE);
  __syncthreads();
}

__global__ __launch_bounds__(NTHR) void k_main(MainArgs a) {
  const int b = blockIdx.x;
  const int t = threadIdx.x;
  const int base_j = b * 8;
  const int r = t >> 4;           // 0..31 : gate*8 + jj
  const int cs = t & 15;
  const int gate = r >> 3;
  const int jj = r & 7;
  const size_t row_g = (size_t)gate * HID + base_j + jj;

  __shared__ float h_lds[HID];
  __shared__ float gsum[32];
  __shared__ float xparr[32];
  __shared__ int toks[2 * TLEN];

  toks[t] = a.x[t];
  toks[TLEN + t] = (t == 0) ? 0 : a.target[t - 1];
  if (t < 8) ATOM_ST(a.h_buf0 + base_j + t, 0.f);   // h0 = 0
  float c_reg = 0.f;                                 // c0 = 0 (held by t<8)

  float4 w4[32];
  {
    const float* wp = a.enc_Whh + row_g * HID + cs * 4;
#pragma unroll
    for (int m = 0; m < 32; ++m) w4[m] = *(const float4*)(wp + m * 64);
  }
  float* hb[2] = {a.h_buf0, a.h_buf1};
  int ping = 0;
  unsigned epoch = 1;
  __syncthreads();                 // drains the h0 atomic stores
  flag_arrive(a.flags, b, epoch);
  flag_wait(a.flags, epoch);

  for (int phase = 0; phase < 2; ++phase) {
    const float* xp = phase ? a.xp_dec : a.xp_enc;
    const int* tk = &toks[phase * TLEN];
    for (int s = 0; s < TLEN; ++s) {
      float* hb_r = hb[ping];
      float* hb_w = hb[ping ^ 1];
      // gather h from LLC (relaxed atomics -> no stale L2 copies possible)
      float hv0 = ATOM_LD(hb_r + t);
      float hv1 = ATOM_LD(hb_r + t + 512);
      float hv2 = ATOM_LD(hb_r + t + 1024);
      float hv3 = ATOM_LD(hb_r + t + 1536);
      float xpv = 0.f;
      if (t < 32) xpv = xp[(size_t)tk[s] * (4 * HID) + (t >> 3) * HID + base_j + (t & 7)];
      h_lds[t] = hv0;
      h_lds[t + 512] = hv1;
      h_lds[t + 1024] = hv2;
      h_lds[t + 1536] = hv3;
      if (t < 32) xparr[t] = xpv;
      __syncthreads();
      float acc = 0.f;
      const float4* h4 = (const float4*)h_lds;
#pragma unroll
      for (int m = 0; m < 32; ++m) {
        float4 hh = h4[(m << 4) + cs];
        float4 ww = w4[m];
        acc = fmaf(ww.x, hh.x, acc);
        acc = fmaf(ww.y, hh.y, acc);
        acc = fmaf(ww.z, hh.z, acc);
        acc = fmaf(ww.w, hh.w, acc);
      }
      acc += __shfl_xor(acc, 1);
      acc += __shfl_xor(acc, 2);
      acc += __shfl_xor(acc, 4);
      acc += __shfl_xor(acc, 8);
      if (cs == 0) gsum[r] = acc;
      __syncthreads();
      // parallel activations: lanes 0-31 of wave 0 (i,f,g,o blocks of 8)
      if (t < 32) {
        float g = gsum[t] + xparr[t];
        bool is_g = (t >= 16) && (t < 24);
        float act = is_g ? tanhf(g) : (1.f / (1.f + expf(-g)));
        float sf = __shfl(act, (t & 7) + 8);
        float tg = __shfl(act, (t & 7) + 16);
        float so = __shfl(act, (t & 7) + 24);
        if (t < 8) {
          float si = act;
          c_reg = sf * c_reg + si * tg;
          float hn = so * tanhf(c_reg);
          ATOM_ST(hb_w + base_j + t, hn);
          if (phase) a.out_dec[(size_t)s * HID + base_j + t] = hn;
        }
      }
      __syncthreads();             // drains the h atomic stores (vmcnt(0))
      ++epoch;
      flag_arrive(a.flags, b, epoch);
      flag_wait(a.flags, epoch);
      ping ^= 1;
    }
    if (phase == 0) {
      // ---- mu / logvar / z (h_enc is in hb[ping]) ----
      {
        float* hsrc = hb[ping];
        h_lds[t]        = ATOM_LD(hsrc + t);
        h_lds[t + 512]  = ATOM_LD(hsrc + t + 512);
        h_lds[t + 1024] = ATOM_LD(hsrc + t + 1024);
        h_lds[t + 1536] = ATOM_LD(hsrc + t + 1536);
      }
      __syncthreads();
      const int r16 = t >> 5, cs32 = t & 31;    // 16 rows x 32 lanes
      const int mrow = base_j + (r16 & 7);
      const float* Wrow = (r16 < 8 ? a.mu_W : a.lv_W) + (size_t)mrow * HID + cs32 * 4;
      float acc = 0.f;
      const float4* h4 = (const float4*)h_lds;
#pragma unroll
      for (int m = 0; m < 16; ++m) {
        float4 wv = *(const float4*)(Wrow + m * 128);
        float4 hh = h4[(m << 5) + cs32];
        acc = fmaf(wv.x, hh.x, acc);
        acc = fmaf(wv.y, hh.y, acc);
        acc = fmaf(wv.z, hh.z, acc);
        acc = fmaf(wv.w, hh.w, acc);
      }
      acc += __shfl_xor(acc, 1);
      acc += __shfl_xor(acc, 2);
      acc += __shfl_xor(acc, 4);
      acc += __shfl_xor(acc, 8);
      acc += __shfl_xor(acc, 16);
      if (cs32 == 0) gsum[r16] = acc + (r16 < 8 ? a.mu_b[mrow] : a.lv_b[mrow]);
      __syncthreads();
      if (t < 8) {
        float mu = gsum[t], lv = gsum[8 + t];
        a.out_mu[base_j + t] = mu;
        a.out_lv[base_j + t] = lv;
        // z -> the buffer nobody reads this phase (hb[ping^1])
        ATOM_ST(hb[ping ^ 1] + base_j + t,
                fmaf(a.eps[base_j + t], expf(0.5f * lv), mu));
      }
      // reload weights for decoder
      {
        const float* wp = a.dec_Whh + row_g * HID + cs * 4;
#pragma unroll
        for (int m = 0; m < 32; ++m) w4[m] = *(const float4*)(wp + m * 64);
      }
      __syncthreads();             // drains z atomic stores
      ++epoch;
      flag_arrive(a.flags, b, epoch);
      flag_wait(a.flags, epoch);
      ping ^= 1;   // decoder reads z from hb[ping]
    }
  }
}

// ---------------------------------------------------------------------------
// Argmax over each dec_outs row (first-index tie semantics, like jnp.argmax)
// ---------------------------------------------------------------------------
__global__ __launch_bounds__(256) void k_argmax(const float* __restrict__ dec,
                                               float* __restrict__ res) {
  const int row = blockIdx.x;
  const int t = threadIdx.x;
  const float4* d4 = (const float4*)(dec + (size_t)row * HID);
  float bv = -INFINITY; int bi = 0;
#pragma unroll
  for (int k = 0; k < 2; ++k) {
    int p = t + k * 256;
    float4 v = d4[p];
    int i0 = p * 4;
    if (v.x > bv) { bv = v.x; bi = i0; }
    if (v.y > bv) { bv = v.y; bi = i0 + 1; }
    if (v.z > bv) { bv = v.z; bi = i0 + 2; }
    if (v.w > bv) { bv = v.w; bi = i0 + 3; }
  }
  for (int off = 1; off < 64; off <<= 1) {
    float ov = __shfl_xor(bv, off);
    int oi = __shfl_xor(bi, off);
    if (ov > bv || (ov == bv && oi < bi)) { bv = ov; bi = oi; }
  }
  __shared__ float sv[4];
  __shared__ int si[4];
  if ((t & 63) == 0) { sv[t >> 6] = bv; si[t >> 6] = bi; }
  __syncthreads();
  if (t == 0) {
    for (int ww = 1; ww < 4; ++ww)
      if (sv[ww] > bv || (sv[ww] == bv && si[ww] < bi)) { bv = sv[ww]; bi = si[ww]; }
    res[row] = (float)bi;
  }
}

// ---------------------------------------------------------------------------
extern "C" void kernel_launch(void* const* d_in, const int* in_sizes, int n_in,
                              void* d_out, int out_size, void* d_ws, size_t ws_size,
                              hipStream_t stream) {
  (void)in_sizes; (void)n_in; (void)out_size; (void)ws_size;
  const int* x        = (const int*)d_in[0];
  const int* target   = (const int*)d_in[1];
  const float* eps    = (const float*)d_in[2];
  const float* enc_emb = (const float*)d_in[3];
  const float* enc_Wih = (const float*)d_in[4];
  const float* enc_Whh = (const float*)d_in[5];
  const float* enc_bih = (const float*)d_in[6];
  const float* enc_bhh = (const float*)d_in[7];
  const float* mu_W   = (const float*)d_in[8];
  const float* mu_b   = (const float*)d_in[9];
  const float* lv_W   = (const float*)d_in[10];
  const float* lv_b   = (const float*)d_in[11];
  const float* dec_emb = (const float*)d_in[12];
  const float* dec_Wih = (const float*)d_in[13];
  const float* dec_Whh = (const float*)d_in[14];
  const float* dec_bih = (const float*)d_in[15];
  const float* dec_bhh = (const float*)d_in[16];

  float* out = (float*)d_out;
  char* ws = (char*)d_ws;
  unsigned* flags = (unsigned*)ws;                     // 256 * 4B = 1 KB
  float* h_buf0 = (float*)(ws + 4096);                 // 8 KB
  float* h_buf1 = h_buf0 + HID;                        // 8 KB
  float* xp_enc = h_buf1 + HID;                        // 28*8192 f32
  float* xp_dec = xp_enc + VOC * 4 * HID;

  hipMemsetAsync(flags, 0, NBLK * 4, stream);
  k_xproj<<<NBLK, 256, 0, stream>>>(enc_emb, enc_Wih, enc_bih, enc_bhh, xp_enc);
  k_xproj<<<NBLK, 256, 0, stream>>>(dec_emb, dec_Wih, dec_bih, dec_bhh, xp_dec);

  MainArgs a;
  a.enc_Whh = enc_Whh; a.dec_Whh = dec_Whh;
  a.x = x; a.target = target; a.eps = eps;
  a.mu_W = mu_W; a.mu_b = mu_b; a.lv_W = lv_W; a.lv_b = lv_b;
  a.xp_enc = xp_enc; a.xp_dec = xp_dec;
  a.h_buf0 = h_buf0; a.h_buf1 = h_buf1;
  a.flags = flags;
  a.out_res = out;
  a.out_dec = out + TLEN;
  a.out_mu  = out + TLEN + (size_t)TLEN * HID;
  a.out_lv  = out + TLEN + (size_t)TLEN * HID + HID;

  void* kargs[] = {(void*)&a};
  hipLaunchCooperativeKernel((void*)k_main, dim3(NBLK), dim3(NTHR), kargs, 0, stream);

  k_argmax<<<TLEN, 256, 0, stream>>>(out + TLEN, out);
}